// Round 5
// baseline (175.582 us; speedup 1.0000x reference)
//
#include <hip/hip_runtime.h>

// TreeRecurrentTagger: B=32, N=1023 nodes (complete heap), HID=128, NCLS=2.
// 3 stream-ordered kernels: subtree up-sweep (levels 8..4), middle (levels
// 3..0 up, g_down, down 0..3, classify 0..14), subtree down-sweep (4..8) +
// classify. Weights in per-thread registers, activations in LDS, fp32 VALU.
//
// R1: kB phased loads (R0 kB spilled at the 256-VGPR cap, 66 MB scratch).
// R2: __launch_bounds__(N,2) — no effect; RA spills to meet its own
//     LDS-derived occupancy target (128-VGPR cap), 2.1 GB scratch.
// R3: fit UNDER the cap: 4-way k-split (64 weight VGPRs), 1024-thr down
//     blocks, LDS sized to pin 4 waves/SIMD. 1853 -> 142.6 µs, 0 spill.
// R5: dot products were LDS-issue-bound: 256 wave-uniform ds_read_b128 per
//     parent per block on one LDS pipe (~12cyc each -> ~3072 cyc/parent).
//     Replace with lane-held ctx (1 spread ds_read_b32 per wave) +
//     v_readlane broadcast feeding the FMAs (VALU pipe). Also parallelize
//     classify (16 thr/node + shfl_xor) instead of 63 serial threads.

constexpr int NNODES = 1023;
constexpr int HB = 128;   // HID

__device__ __forceinline__ float bcast(float v, int k) {
  return __int_as_float(__builtin_amdgcn_readlane(__float_as_int(v), k));
}

// ---------- up level, readlane form (kernel A; NQ=4, 512 thr) ----------
// i = t&127 (output row), q = t>>7 (k-quarter), lane = t&63.
// ctx of parent (base+p) = 256 contiguous floats at node (cb+2p).
// Lane l holds ctx[q*64+l]; v_readlane broadcasts each element to the wave.
template<int NP>
__device__ __forceinline__ void up_rl(float* __restrict__ heap,
                                      float* __restrict__ red,
                                      const float4 (&w)[16],
                                      float bci, int i, int q, int lane) {
  constexpr int base = NP - 1, cb = 2 * NP - 1;
  constexpr int CH = (NP < 4) ? NP : 4;
#pragma unroll
  for (int c = 0; c < NP; c += CH) {
    float ctxr[CH], acc[CH];
#pragma unroll
    for (int j = 0; j < CH; ++j) {
      ctxr[j] = heap[(cb + 2 * (c + j)) * HB + q * 64 + lane];
      acc[j] = 0.f;
    }
#pragma unroll
    for (int k4 = 0; k4 < 16; ++k4) {
      const float4 wv = w[k4];
#pragma unroll
      for (int cc = 0; cc < 4; ++cc) {
        const float wk = (cc == 0) ? wv.x : (cc == 1) ? wv.y : (cc == 2) ? wv.z : wv.w;
        const int k = k4 * 4 + cc;
#pragma unroll
        for (int j = 0; j < CH; ++j)
          acc[j] = fmaf(wk, bcast(ctxr[j], k), acc[j]);
      }
    }
    if (q) {
#pragma unroll
      for (int j = 0; j < CH; ++j) red[((q - 1) * CH + j) * HB + i] = acc[j];
    }
    __syncthreads();
    if (!q) {
#pragma unroll
      for (int j = 0; j < CH; ++j) {
        float s = acc[j] + bci;
#pragma unroll
        for (int m = 0; m < 3; ++m) s += red[(m * CH + j) * HB + i];
        heap[(base + c + j) * HB + i] = tanhf(s);
      }
    }
    __syncthreads();
  }
}

// ---------- up level, broadcast form (kernel B up phase; NQ=8, 1024 thr) ----------
template<int NP, int NQ>
__device__ __forceinline__ void up4(float* __restrict__ heap,
                                    float* __restrict__ red,
                                    const float4 (&w)[64 / NQ],
                                    float bci, int i, int q) {
  constexpr int base = NP - 1, cb = 2 * NP - 1;
  constexpr int CH = (NP < 4) ? NP : 4;
  constexpr int K4 = 64 / NQ;
#pragma unroll
  for (int c = 0; c < NP; c += CH) {
    float acc[CH];
#pragma unroll
    for (int j = 0; j < CH; ++j) acc[j] = 0.f;
    const float* ctx0 = heap + (cb + 2 * c) * HB + q * (256 / NQ);
#pragma unroll
    for (int k4 = 0; k4 < K4; ++k4) {
      const float4 wv = w[k4];
#pragma unroll
      for (int j = 0; j < CH; ++j) {
        const float4 cc = *(const float4*)(ctx0 + j * 2 * HB + k4 * 4);
        acc[j] = fmaf(wv.x, cc.x, fmaf(wv.y, cc.y, fmaf(wv.z, cc.z, fmaf(wv.w, cc.w, acc[j]))));
      }
    }
    if (q) {
#pragma unroll
      for (int j = 0; j < CH; ++j) red[((q - 1) * CH + j) * HB + i] = acc[j];
    }
    __syncthreads();
    if (!q) {
#pragma unroll
      for (int j = 0; j < CH; ++j) {
        float s = acc[j] + bci;
#pragma unroll
        for (int m = 0; m < NQ - 1; ++m) s += red[(m * CH + j) * HB + i];
        heap[(base + c + j) * HB + i] = tanhf(s);
      }
    }
    __syncthreads();
  }
}

// ---------- down level, readlane form (kernels B and C; 1024 thr) ----------
// i = t&255 (output row), q = t>>8 (k-quarter; 0,1 read down-ctx, 2,3 up-ctx),
// lane = t&63. Row i<128 -> left child, i>=128 -> right child.
template<int NP>
__device__ __forceinline__ void down_rl(float* __restrict__ db,
                                        const float* __restrict__ ub,
                                        float* __restrict__ red,
                                        const float4 (&w)[16],
                                        float bdi, int i, int q, int lane) {
  constexpr int base = NP - 1, cb = 2 * NP - 1;
  constexpr int CH = (NP < 4) ? NP : 4;
#pragma unroll
  for (int c = 0; c < NP; c += CH) {
    float ctxr[CH], acc[CH];
#pragma unroll
    for (int j = 0; j < CH; ++j) {
      const float* srcj = (q < 2 ? db : ub) + (base + c + j) * HB + (q & 1) * 64;
      ctxr[j] = srcj[lane];
      acc[j] = 0.f;
    }
#pragma unroll
    for (int k4 = 0; k4 < 16; ++k4) {
      const float4 wv = w[k4];
#pragma unroll
      for (int cc = 0; cc < 4; ++cc) {
        const float wk = (cc == 0) ? wv.x : (cc == 1) ? wv.y : (cc == 2) ? wv.z : wv.w;
        const int k = k4 * 4 + cc;
#pragma unroll
        for (int j = 0; j < CH; ++j)
          acc[j] = fmaf(wk, bcast(ctxr[j], k), acc[j]);
      }
    }
    if (q) {
#pragma unroll
      for (int j = 0; j < CH; ++j) red[((q - 1) * CH + j) * 256 + i] = acc[j];
    }
    __syncthreads();
    if (!q) {
#pragma unroll
      for (int j = 0; j < CH; ++j) {
        const float v = tanhf(acc[j] + red[j * 256 + i] + red[(CH + j) * 256 + i] +
                              red[(2 * CH + j) * 256 + i] + bdi);
        db[(cb + 2 * (c + j) + (i >> 7)) * HB + (i & 127)] = v;
      }
    }
    __syncthreads();
  }
}

// ---------- classifier, 16 threads/node + shfl_xor reduce ----------
// softmax(sigmoid(Wcl @ [down, up] + bcl)); un==nullptr -> up part is zero.
__device__ __forceinline__ void classify16(const float* __restrict__ dn,
                                           const float* __restrict__ un,
                                           const float* __restrict__ wcl,
                                           const float* __restrict__ bcl,
                                           float* __restrict__ o, int l16) {
  float s0 = 0.f, s1 = 0.f;
  const int k0 = l16 * 8;
#pragma unroll
  for (int k = 0; k < 8; ++k) {
    const float dv = dn[k0 + k];
    s0 = fmaf(dv, wcl[k0 + k], s0);
    s1 = fmaf(dv, wcl[256 + k0 + k], s1);
  }
  if (un) {
#pragma unroll
    for (int k = 0; k < 8; ++k) {
      const float uv = un[k0 + k];
      s0 = fmaf(uv, wcl[128 + k0 + k], s0);
      s1 = fmaf(uv, wcl[384 + k0 + k], s1);
    }
  }
#pragma unroll
  for (int m = 8; m >= 1; m >>= 1) {   // stays within the 16-lane group
    s0 += __shfl_xor(s0, m);
    s1 += __shfl_xor(s1, m);
  }
  if (l16 == 0) {
    s0 += bcl[0]; s1 += bcl[1];
    const float p0 = 1.f / (1.f + expf(-s0));
    const float p1 = 1.f / (1.f + expf(-s1));
    const float mx = fmaxf(p0, p1);
    const float e0 = expf(p0 - mx), e1 = expf(p1 - mx);
    const float inv = 1.f / (e0 + e1);
    o[0] = e0 * inv;
    o[1] = e1 * inv;
  }
}

// ================= Kernel A: leaf gather + up levels 8..4 =================
// grid = 32*16 (batch, level-4 subtree); subtree root r = 15+s.
// 512 thr: i = t&127, q = t>>7 (4-way k-split). ~60 KB LDS -> 2 blocks/CU.
__global__ __launch_bounds__(512, 4) void kA_up(const int* __restrict__ x,
                                                const int* __restrict__ cue,
                                                const float* __restrict__ emb,
                                                const float* __restrict__ Wc,
                                                const float* __restrict__ bc,
                                                float* __restrict__ hw) {
  __shared__ __align__(16) float heap[63 * HB];
  __shared__ __align__(16) float red[7296];   // 1536 used; oversized to pin occupancy
  const int b = blockIdx.x >> 4, s = blockIdx.x & 15, r = 15 + s;
  const int t = threadIdx.x, i = t & 127, q = t >> 7, lane = t & 63;

  float4 w[16];
  const float4* wrow = (const float4*)(Wc + i * 256 + q * 64);
#pragma unroll
  for (int k = 0; k < 16; ++k) w[k] = wrow[k];
  const float bci = bc[i];

  // leaf features: [emb[x] (126) | one_hot(cue,2)]
  for (int idx = t; idx < 32 * HB; idx += 512) {
    const int j = idx >> 7, k = idx & 127;
    const int g = ((r + 1) << 5) - 1 + j;      // global leaf node (511..1022)
    float v;
    if (k < 126) v = emb[(long long)x[b * NNODES + g] * 126 + k];
    else         v = (cue[b * NNODES + g] == (k - 126)) ? 1.f : 0.f;
    heap[(31 + j) * HB + k] = v;
  }
  __syncthreads();

  up_rl<16>(heap, red, w, bci, i, q, lane);
  up_rl<8>(heap, red, w, bci, i, q, lane);
  up_rl<4>(heap, red, w, bci, i, q, lane);
  up_rl<2>(heap, red, w, bci, i, q, lane);
  up_rl<1>(heap, red, w, bci, i, q, lane);

  float* dst = hw + (size_t)(b * 16 + s) * 31 * HB;
  for (int idx = t; idx < 31 * HB; idx += 512) dst[idx] = heap[idx];
}

// ================= Kernel B: up 3..0, g_down, down 0..3, classify 0..14 =================
// 1024 thr, one block per batch. Up phase: 8-way broadcast k-split.
// Down phase: readlane form. >80 KB LDS -> 1 block/CU -> RA reg cap 128.
__global__ __launch_bounds__(1024, 4) void kB_mid(const float* __restrict__ Wc,
                                                  const float* __restrict__ bc,
                                                  const float* __restrict__ Wg,
                                                  const float* __restrict__ bg,
                                                  const float* __restrict__ Wd,
                                                  const float* __restrict__ bd,
                                                  const float* __restrict__ Wcl,
                                                  const float* __restrict__ bcl,
                                                  const float* __restrict__ hw,
                                                  float* __restrict__ dw,
                                                  float* __restrict__ out) {
  __shared__ __align__(16) float ub[31 * HB];   // up h, nodes 0..30
  __shared__ __align__(16) float db[31 * HB];   // down, nodes 0..30
  __shared__ __align__(16) float red[12084];    // 3072 used; oversized to pin occupancy
  __shared__ __align__(16) float wcl[512];
  const int b = blockIdx.x, t = threadIdx.x;

  // level-4 h (root of each subtree s) -> ub[15..30]
  for (int idx = t; idx < 16 * HB; idx += 1024)
    ub[15 * HB + idx] = hw[(size_t)(b * 16 + (idx >> 7)) * 31 * HB + (idx & 127)];
  if (t < 512) wcl[t] = Wcl[t];
  __syncthreads();

  // ---- up levels 3..0 (8-way broadcast k-split) + g_down ----
  {
    const int i = t & 127, q = t >> 7;           // q in 0..7
    float4 wu[8];
    const float4* wrow = (const float4*)(Wc + i * 256 + q * 32);
#pragma unroll
    for (int k = 0; k < 8; ++k) wu[k] = wrow[k];
    const float bci = bc[i];
    up4<8, 8>(ub, red, wu, bci, i, q);
    up4<4, 8>(ub, red, wu, bci, i, q);
    up4<2, 8>(ub, red, wu, bci, i, q);
    up4<1, 8>(ub, red, wu, bci, i, q);

    // g_down = sigmoid(Wg @ h_root + bg), 8-way split of 128-wide ctx
    float4 wg[4];
    const float4* wgrow = (const float4*)(Wg + i * 128 + q * 16);
#pragma unroll
    for (int k = 0; k < 4; ++k) wg[k] = wgrow[k];
    float acc = 0.f;
#pragma unroll
    for (int k4 = 0; k4 < 4; ++k4) {
      const float4 cc = *(const float4*)(ub + q * 16 + k4 * 4);
      const float4 wv = wg[k4];
      acc = fmaf(wv.x, cc.x, fmaf(wv.y, cc.y, fmaf(wv.z, cc.z, fmaf(wv.w, cc.w, acc))));
    }
    if (q) red[(q - 1) * 128 + i] = acc;
    __syncthreads();
    if (!q) {
      float sum = acc + bg[i];
#pragma unroll
      for (int m = 0; m < 7; ++m) sum += red[m * 128 + i];
      db[i] = 1.f / (1.f + expf(-sum));
    }
    __syncthreads();
  }
  asm volatile("" ::: "memory");  // keep Wd loads from hoisting into the up phase

  // ---- down levels 0..3 (readlane form) ----
  {
    const int i = t & 255, q = t >> 8, lane = t & 63;
    float4 w[16];
    const float4* wrow = (const float4*)(Wd + i * 256 + q * 64);
#pragma unroll
    for (int k = 0; k < 16; ++k) w[k] = wrow[k];
    const float bdi = bd[i];
    down_rl<1>(db, ub, red, w, bdi, i, q, lane);
    down_rl<2>(db, ub, red, w, bdi, i, q, lane);
    down_rl<4>(db, ub, red, w, bdi, i, q, lane);
    down_rl<8>(db, ub, red, w, bdi, i, q, lane);
  }

  // persist level-4 down (nodes 15..30) for kernel C
  for (int idx = t; idx < 16 * HB; idx += 1024)
    dw[(size_t)(b * 16 + (idx >> 7)) * HB + (idx & 127)] = db[15 * HB + idx];

  // classify global nodes 0..14 (16 threads per node)
  if (t < 15 * 16) {
    const int m = t >> 4;
    classify16(db + m * HB, ub + m * HB, wcl, bcl,
               out + ((size_t)b * NNODES + m) * 2, t & 15);
  }
}

// ================= Kernel C: down levels 4..8 + classify 63 subtree nodes =================
// 1024 thr: i = t&255, q = t>>8 (readlane form).
__global__ __launch_bounds__(1024, 4) void kC_down(const float* __restrict__ Wd,
                                                   const float* __restrict__ bd,
                                                   const float* __restrict__ Wcl,
                                                   const float* __restrict__ bcl,
                                                   const float* __restrict__ hw,
                                                   const float* __restrict__ dw,
                                                   float* __restrict__ out) {
  __shared__ __align__(16) float ub[31 * HB];   // up h, local nodes 0..30
  __shared__ __align__(16) float db[63 * HB];   // down, local nodes 0..62
  __shared__ __align__(16) float red[7960];     // 3072 used; oversized to pin occupancy
  __shared__ __align__(16) float wcl[512];
  const int b = blockIdx.x >> 4, s = blockIdx.x & 15, r = 15 + s;
  const int t = threadIdx.x, i = t & 255, q = t >> 8, lane = t & 63;

  float4 w[16];
  const float4* wrow = (const float4*)(Wd + i * 256 + q * 64);
#pragma unroll
  for (int k = 0; k < 16; ++k) w[k] = wrow[k];
  const float bdi = bd[i];

  const float* src = hw + (size_t)(b * 16 + s) * 31 * HB;
  for (int idx = t; idx < 31 * HB; idx += 1024) ub[idx] = src[idx];
  if (t < HB) db[t] = dw[(size_t)(b * 16 + s) * HB + t];   // down at subtree root
  if (t < 512) wcl[t] = Wcl[t];
  __syncthreads();

  down_rl<1>(db, ub, red, w, bdi, i, q, lane);
  down_rl<2>(db, ub, red, w, bdi, i, q, lane);
  down_rl<4>(db, ub, red, w, bdi, i, q, lane);
  down_rl<8>(db, ub, red, w, bdi, i, q, lane);
  down_rl<16>(db, ub, red, w, bdi, i, q, lane);

  // classify local heap nodes 0..62 (16 threads per node); leaves have up = 0
  if (t < 63 * 16) {
    const int m = t >> 4;
    const int lvl = 31 - __clz(m + 1);
    const int j = (m + 1) - (1 << lvl);
    const int g = ((r + 1) << lvl) - 1 + j;
    classify16(db + m * HB, (m < 31) ? (ub + m * HB) : nullptr, wcl, bcl,
               out + ((size_t)b * NNODES + g) * 2, t & 15);
  }
}

extern "C" void kernel_launch(void* const* d_in, const int* in_sizes, int n_in,
                              void* d_out, int out_size, void* d_ws, size_t ws_size,
                              hipStream_t stream) {
  const int*   x   = (const int*)d_in[0];
  // d_in[1] word_index: identity leaf mapping (leaf j at node 511+j) -- unused
  const int*   cue = (const int*)d_in[2];
  // d_in[3] adj: encodes the same hardcoded heap tree -- unused
  const float* emb = (const float*)d_in[4];
  const float* Wc  = (const float*)d_in[5];
  const float* bc  = (const float*)d_in[6];
  const float* Wd  = (const float*)d_in[7];
  const float* bd  = (const float*)d_in[8];
  const float* Wg  = (const float*)d_in[9];
  const float* bg  = (const float*)d_in[10];
  const float* Wcl = (const float*)d_in[11];
  const float* bcl = (const float*)d_in[12];
  float* out = (float*)d_out;

  float* hw = (float*)d_ws;                       // [B][16][31][128] up h
  float* dw = hw + (size_t)32 * 16 * 31 * 128;    // [B][16][128] level-4 down

  hipLaunchKernelGGL(kA_up,   dim3(512), dim3(512), 0, stream, x, cue, emb, Wc, bc, hw);
  hipLaunchKernelGGL(kB_mid,  dim3(32),  dim3(1024), 0, stream,
                     Wc, bc, Wg, bg, Wd, bd, Wcl, bcl, hw, dw, out);
  hipLaunchKernelGGL(kC_down, dim3(512), dim3(1024), 0, stream,
                     Wd, bd, Wcl, bcl, hw, dw, out);
}

// Round 6
// 100.192 us; speedup vs baseline: 1.7525x; 1.7525x over previous
//
#include <hip/hip_runtime.h>

// TreeRecurrentTagger: B=32, N=1023 nodes (complete heap), HID=128, NCLS=2.
// 3 stream-ordered kernels: subtree up-sweep (levels 8..4), middle (levels
// 3..0 up, g_down, down 0..3, classify 0..14), subtree down-sweep (4..8) +
// classify. Weights in per-thread registers, activations in LDS, fp32 VALU.
//
// R3: fit under the RA's 128-VGPR occupancy target (4-way k-split, 64 weight
//     VGPRs; LDS sized to pin 4 waves/SIMD). 1853 -> 142.6 µs, 0 spill.
// R4: readlane broadcast form — REGRESSED (175 µs): wave-uniform ds_read is
//     the free same-address broadcast; readlane just doubled VALU. Reverted.
// R5: granule-interleaved k-split (thread owns 16B granules q+4m) so the 4
//     k-partials of a row sit in adjacent lanes: reduce via 2 __shfl_xor
//     in-register. Removes the LDS `red` round-trip and drops barriers from
//     2/chunk to 1/level. Spread ds_read_b128 addresses land on distinct
//     bank-quads (4q+16m mod 32) -> conflict-free.

constexpr int NNODES = 1023;
constexpr int HB = 128;   // HID

// ---------- up level, shfl form (512 thr: i = t>>2, q = t&3) ----------
// out[base+p] = tanh(Wc @ [h_left, h_right] + bc); children of local node
// (base+p) at (cb+2p),(cb+2p+1) -> 256 contiguous floats.
// Thread (i,q) owns k-granules q+4m (floats q*4+16m .. +3), m = 0..15.
template<int NP>
__device__ __forceinline__ void up_s(float* __restrict__ heap,
                                     const float4 (&w)[16],
                                     float bci, int i, int q) {
  constexpr int base = NP - 1, cb = 2 * NP - 1;
  constexpr int CH = (NP < 4) ? NP : 4;
#pragma unroll
  for (int c = 0; c < NP; c += CH) {
    float acc[CH];
#pragma unroll
    for (int j = 0; j < CH; ++j) acc[j] = 0.f;
#pragma unroll
    for (int m = 0; m < 16; ++m) {
      const float4 wv = w[m];
#pragma unroll
      for (int j = 0; j < CH; ++j) {
        const float4 cc = *(const float4*)(heap + (cb + 2 * (c + j)) * HB + q * 4 + m * 16);
        acc[j] = fmaf(wv.x, cc.x, fmaf(wv.y, cc.y, fmaf(wv.z, cc.z, fmaf(wv.w, cc.w, acc[j]))));
      }
    }
#pragma unroll
    for (int j = 0; j < CH; ++j) {
      acc[j] += __shfl_xor(acc[j], 1);
      acc[j] += __shfl_xor(acc[j], 2);
    }
    if (q < CH) {                      // lane q writes parent c+q
      float v = acc[0];
#pragma unroll
      for (int j = 1; j < CH; ++j) if (q == j) v = acc[j];
      heap[(base + c + q) * HB + i] = tanhf(v + bci);
    }
  }
  __syncthreads();
}

// ---------- up level, 8-way shfl form (kB, 1024 thr: i = t>>3, o = t&7) ----------
// Thread (i,o) owns granules o+8m (floats o*4+32m .. +3), m = 0..7.
template<int NP>
__device__ __forceinline__ void up8(float* __restrict__ heap,
                                    const float4 (&w)[8],
                                    float bci, int i, int o) {
  constexpr int base = NP - 1, cb = 2 * NP - 1;
  constexpr int CH = (NP < 8) ? NP : 8;
#pragma unroll
  for (int c = 0; c < NP; c += CH) {
    float acc[CH];
#pragma unroll
    for (int j = 0; j < CH; ++j) acc[j] = 0.f;
#pragma unroll
    for (int m = 0; m < 8; ++m) {
      const float4 wv = w[m];
#pragma unroll
      for (int j = 0; j < CH; ++j) {
        const float4 cc = *(const float4*)(heap + (cb + 2 * (c + j)) * HB + o * 4 + m * 32);
        acc[j] = fmaf(wv.x, cc.x, fmaf(wv.y, cc.y, fmaf(wv.z, cc.z, fmaf(wv.w, cc.w, acc[j]))));
      }
    }
#pragma unroll
    for (int j = 0; j < CH; ++j) {
      acc[j] += __shfl_xor(acc[j], 1);
      acc[j] += __shfl_xor(acc[j], 2);
      acc[j] += __shfl_xor(acc[j], 4);
    }
    if (o < CH) {
      float v = acc[0];
#pragma unroll
      for (int j = 1; j < CH; ++j) if (o == j) v = acc[j];
      heap[(base + c + o) * HB + i] = tanhf(v + bci);
    }
  }
  __syncthreads();
}

// ---------- down level, shfl form (1024 thr: i = t>>2, q = t&3) ----------
// ch = tanh(Wd @ [down_p, up_p] + bd); logical ctx granule g = q+4m:
// g < 32 (m < 8) -> down part, g >= 32 (m >= 8) -> up part.
// Row i<128 -> left child, i>=128 -> right child.
template<int NP>
__device__ __forceinline__ void down_s(float* __restrict__ db,
                                       const float* __restrict__ ub,
                                       const float4 (&w)[16],
                                       float bdi, int i, int q) {
  constexpr int base = NP - 1, cb = 2 * NP - 1;
  constexpr int CH = (NP < 4) ? NP : 4;
#pragma unroll
  for (int c = 0; c < NP; c += CH) {
    float acc[CH];
#pragma unroll
    for (int j = 0; j < CH; ++j) acc[j] = 0.f;
#pragma unroll
    for (int m = 0; m < 16; ++m) {
      const float4 wv = w[m];
#pragma unroll
      for (int j = 0; j < CH; ++j) {
        const float* srcj = (m < 8)
            ? (db + (base + c + j) * HB + q * 4 + m * 16)
            : (ub + (base + c + j) * HB + q * 4 + (m - 8) * 16);
        const float4 cc = *(const float4*)srcj;
        acc[j] = fmaf(wv.x, cc.x, fmaf(wv.y, cc.y, fmaf(wv.z, cc.z, fmaf(wv.w, cc.w, acc[j]))));
      }
    }
#pragma unroll
    for (int j = 0; j < CH; ++j) {
      acc[j] += __shfl_xor(acc[j], 1);
      acc[j] += __shfl_xor(acc[j], 2);
    }
    if (q < CH) {                      // lane q writes parent c+q's child row
      float v = acc[0];
#pragma unroll
      for (int j = 1; j < CH; ++j) if (q == j) v = acc[j];
      db[(cb + 2 * (c + q) + (i >> 7)) * HB + (i & 127)] = tanhf(v + bdi);
    }
  }
  __syncthreads();
}

// ---------- classifier, 16 threads/node + shfl_xor reduce ----------
// softmax(sigmoid(Wcl @ [down, up] + bcl)); un==nullptr -> up part is zero.
__device__ __forceinline__ void classify16(const float* __restrict__ dn,
                                           const float* __restrict__ un,
                                           const float* __restrict__ wcl,
                                           const float* __restrict__ bcl,
                                           float* __restrict__ o, int l16) {
  float s0 = 0.f, s1 = 0.f;
  const int k0 = l16 * 8;
#pragma unroll
  for (int k = 0; k < 8; ++k) {
    const float dv = dn[k0 + k];
    s0 = fmaf(dv, wcl[k0 + k], s0);
    s1 = fmaf(dv, wcl[256 + k0 + k], s1);
  }
  if (un) {
#pragma unroll
    for (int k = 0; k < 8; ++k) {
      const float uv = un[k0 + k];
      s0 = fmaf(uv, wcl[128 + k0 + k], s0);
      s1 = fmaf(uv, wcl[384 + k0 + k], s1);
    }
  }
#pragma unroll
  for (int m = 8; m >= 1; m >>= 1) {   // stays within the 16-lane group
    s0 += __shfl_xor(s0, m);
    s1 += __shfl_xor(s1, m);
  }
  if (l16 == 0) {
    s0 += bcl[0]; s1 += bcl[1];
    const float p0 = 1.f / (1.f + expf(-s0));
    const float p1 = 1.f / (1.f + expf(-s1));
    const float mx = fmaxf(p0, p1);
    const float e0 = expf(p0 - mx), e1 = expf(p1 - mx);
    const float inv = 1.f / (e0 + e1);
    o[0] = e0 * inv;
    o[1] = e1 * inv;
  }
}

// ================= Kernel A: leaf gather + up levels 8..4 =================
// grid = 32*16 (batch, level-4 subtree); subtree root r = 15+s.
// 512 thr: i = t>>2, q = t&3. ~60 KB LDS -> 2 blocks/CU (pins RA target).
__global__ __launch_bounds__(512, 4) void kA_up(const int* __restrict__ x,
                                                const int* __restrict__ cue,
                                                const float* __restrict__ emb,
                                                const float* __restrict__ Wc,
                                                const float* __restrict__ bc,
                                                float* __restrict__ hw) {
  __shared__ __align__(16) float heap[63 * HB];
  __shared__ __align__(16) float pad[7296];   // unused; pins occupancy via LDS
  const int b = blockIdx.x >> 4, s = blockIdx.x & 15, r = 15 + s;
  const int t = threadIdx.x, i = t >> 2, q = t & 3;
  if (t == 0) ((volatile float*)pad)[0] = 0.f;

  float4 w[16];
#pragma unroll
  for (int m = 0; m < 16; ++m)
    w[m] = *(const float4*)(Wc + i * 256 + q * 4 + m * 16);
  const float bci = bc[i];

  // leaf features: [emb[x] (126) | one_hot(cue,2)]
  for (int idx = t; idx < 32 * HB; idx += 512) {
    const int j = idx >> 7, k = idx & 127;
    const int g = ((r + 1) << 5) - 1 + j;      // global leaf node (511..1022)
    float v;
    if (k < 126) v = emb[(long long)x[b * NNODES + g] * 126 + k];
    else         v = (cue[b * NNODES + g] == (k - 126)) ? 1.f : 0.f;
    heap[(31 + j) * HB + k] = v;
  }
  __syncthreads();

  up_s<16>(heap, w, bci, i, q);
  up_s<8>(heap, w, bci, i, q);
  up_s<4>(heap, w, bci, i, q);
  up_s<2>(heap, w, bci, i, q);
  up_s<1>(heap, w, bci, i, q);

  float* dst = hw + (size_t)(b * 16 + s) * 31 * HB;
  for (int idx = t; idx < 31 * HB; idx += 512) dst[idx] = heap[idx];
}

// ================= Kernel B: up 3..0, g_down, down 0..3, classify 0..14 =================
// 1024 thr, one block per batch. Up phase 8-way shfl split, down phase 4-way.
// >80 KB LDS -> 1 block/CU -> RA reg cap 128; phased weight loads.
__global__ __launch_bounds__(1024, 4) void kB_mid(const float* __restrict__ Wc,
                                                  const float* __restrict__ bc,
                                                  const float* __restrict__ Wg,
                                                  const float* __restrict__ bg,
                                                  const float* __restrict__ Wd,
                                                  const float* __restrict__ bd,
                                                  const float* __restrict__ Wcl,
                                                  const float* __restrict__ bcl,
                                                  const float* __restrict__ hw,
                                                  float* __restrict__ dw,
                                                  float* __restrict__ out) {
  __shared__ __align__(16) float ub[31 * HB];   // up h, nodes 0..30
  __shared__ __align__(16) float db[31 * HB];   // down, nodes 0..30
  __shared__ __align__(16) float pad[12084];    // unused; pins occupancy via LDS
  __shared__ __align__(16) float wcl[512];
  const int b = blockIdx.x, t = threadIdx.x;
  if (t == 0) ((volatile float*)pad)[0] = 0.f;

  // level-4 h (root of each subtree s) -> ub[15..30]
  for (int idx = t; idx < 16 * HB; idx += 1024)
    ub[15 * HB + idx] = hw[(size_t)(b * 16 + (idx >> 7)) * 31 * HB + (idx & 127)];
  if (t < 512) wcl[t] = Wcl[t];
  __syncthreads();

  // ---- up levels 3..0 (8-way shfl split) + g_down ----
  {
    const int i = t >> 3, o = t & 7;
    float4 wu[8];
#pragma unroll
    for (int m = 0; m < 8; ++m)
      wu[m] = *(const float4*)(Wc + i * 256 + o * 4 + m * 32);
    const float bci = bc[i];
    up8<8>(ub, wu, bci, i, o);
    up8<4>(ub, wu, bci, i, o);
    up8<2>(ub, wu, bci, i, o);
    up8<1>(ub, wu, bci, i, o);

    // g_down = sigmoid(Wg @ h_root + bg): granules o+8m of 128-wide ctx
    float4 wg[4];
#pragma unroll
    for (int m = 0; m < 4; ++m)
      wg[m] = *(const float4*)(Wg + i * 128 + o * 4 + m * 32);
    float acc = 0.f;
#pragma unroll
    for (int m = 0; m < 4; ++m) {
      const float4 cc = *(const float4*)(ub + o * 4 + m * 32);
      const float4 wv = wg[m];
      acc = fmaf(wv.x, cc.x, fmaf(wv.y, cc.y, fmaf(wv.z, cc.z, fmaf(wv.w, cc.w, acc))));
    }
    acc += __shfl_xor(acc, 1);
    acc += __shfl_xor(acc, 2);
    acc += __shfl_xor(acc, 4);
    if (o == 0) db[i] = 1.f / (1.f + expf(-(acc + bg[i])));
    __syncthreads();
  }
  asm volatile("" ::: "memory");  // keep Wd loads from hoisting into the up phase

  // ---- down levels 0..3 (4-way shfl split) ----
  {
    const int i = t >> 2, q = t & 3;
    float4 w[16];
#pragma unroll
    for (int m = 0; m < 16; ++m)
      w[m] = *(const float4*)(Wd + i * 256 + q * 4 + m * 16);
    const float bdi = bd[i];
    down_s<1>(db, ub, w, bdi, i, q);
    down_s<2>(db, ub, w, bdi, i, q);
    down_s<4>(db, ub, w, bdi, i, q);
    down_s<8>(db, ub, w, bdi, i, q);
  }

  // persist level-4 down (nodes 15..30) for kernel C
  for (int idx = t; idx < 16 * HB; idx += 1024)
    dw[(size_t)(b * 16 + (idx >> 7)) * HB + (idx & 127)] = db[15 * HB + idx];

  // classify global nodes 0..14 (16 threads per node)
  if (t < 15 * 16) {
    const int m = t >> 4;
    classify16(db + m * HB, ub + m * HB, wcl, bcl,
               out + ((size_t)b * NNODES + m) * 2, t & 15);
  }
}

// ================= Kernel C: down levels 4..8 + classify 63 subtree nodes =================
// 1024 thr: i = t>>2, q = t&3 (4-way shfl split). >80 KB LDS -> 1 block/CU.
__global__ __launch_bounds__(1024, 4) void kC_down(const float* __restrict__ Wd,
                                                   const float* __restrict__ bd,
                                                   const float* __restrict__ Wcl,
                                                   const float* __restrict__ bcl,
                                                   const float* __restrict__ hw,
                                                   const float* __restrict__ dw,
                                                   float* __restrict__ out) {
  __shared__ __align__(16) float ub[31 * HB];   // up h, local nodes 0..30
  __shared__ __align__(16) float db[63 * HB];   // down, local nodes 0..62
  __shared__ __align__(16) float pad[7960];     // unused; pins occupancy via LDS
  __shared__ __align__(16) float wcl[512];
  const int b = blockIdx.x >> 4, s = blockIdx.x & 15, r = 15 + s;
  const int t = threadIdx.x, i = t >> 2, q = t & 3;
  if (t == 0) ((volatile float*)pad)[0] = 0.f;

  float4 w[16];
#pragma unroll
  for (int m = 0; m < 16; ++m)
    w[m] = *(const float4*)(Wd + i * 256 + q * 4 + m * 16);
  const float bdi = bd[i];

  const float* src = hw + (size_t)(b * 16 + s) * 31 * HB;
  for (int idx = t; idx < 31 * HB; idx += 1024) ub[idx] = src[idx];
  if (t < HB) db[t] = dw[(size_t)(b * 16 + s) * HB + t];   // down at subtree root
  if (t < 512) wcl[t] = Wcl[t];
  __syncthreads();

  down_s<1>(db, ub, w, bdi, i, q);
  down_s<2>(db, ub, w, bdi, i, q);
  down_s<4>(db, ub, w, bdi, i, q);
  down_s<8>(db, ub, w, bdi, i, q);
  down_s<16>(db, ub, w, bdi, i, q);

  // classify local heap nodes 0..62 (16 threads per node); leaves have up = 0
  if (t < 63 * 16) {
    const int m = t >> 4;
    const int lvl = 31 - __clz(m + 1);
    const int j = (m + 1) - (1 << lvl);
    const int g = ((r + 1) << lvl) - 1 + j;
    classify16(db + m * HB, (m < 31) ? (ub + m * HB) : nullptr, wcl, bcl,
               out + ((size_t)b * NNODES + g) * 2, t & 15);
  }
}

extern "C" void kernel_launch(void* const* d_in, const int* in_sizes, int n_in,
                              void* d_out, int out_size, void* d_ws, size_t ws_size,
                              hipStream_t stream) {
  const int*   x   = (const int*)d_in[0];
  // d_in[1] word_index: identity leaf mapping (leaf j at node 511+j) -- unused
  const int*   cue = (const int*)d_in[2];
  // d_in[3] adj: encodes the same hardcoded heap tree -- unused
  const float* emb = (const float*)d_in[4];
  const float* Wc  = (const float*)d_in[5];
  const float* bc  = (const float*)d_in[6];
  const float* Wd  = (const float*)d_in[7];
  const float* bd  = (const float*)d_in[8];
  const float* Wg  = (const float*)d_in[9];
  const float* bg  = (const float*)d_in[10];
  const float* Wcl = (const float*)d_in[11];
  const float* bcl = (const float*)d_in[12];
  float* out = (float*)d_out;

  float* hw = (float*)d_ws;                       // [B][16][31][128] up h
  float* dw = hw + (size_t)32 * 16 * 31 * 128;    // [B][16][128] level-4 down

  hipLaunchKernelGGL(kA_up,   dim3(512), dim3(512), 0, stream, x, cue, emb, Wc, bc, hw);
  hipLaunchKernelGGL(kB_mid,  dim3(32),  dim3(1024), 0, stream,
                     Wc, bc, Wg, bg, Wd, bd, Wcl, bcl, hw, dw, out);
  hipLaunchKernelGGL(kC_down, dim3(512), dim3(1024), 0, stream,
                     Wd, bd, Wcl, bcl, hw, dw, out);
}

// Round 8
// 80.608 us; speedup vs baseline: 2.1782x; 1.2429x over previous
//
#include <hip/hip_runtime.h>

// TreeRecurrentTagger: B=32, N=1023 nodes (complete heap), HID=128, NCLS=2.
// 3 stream-ordered kernels. Weights in per-thread registers, activations in
// LDS, fp32 VALU.
//
// R3: fit under the RA's 128-VGPR occupancy target. 1853 -> 142.6 µs.
// R4: readlane broadcast — regressed (175): broadcast ds_read is free. Revert.
// R5: granule-interleaved k-split + shfl_xor reduce. 142.6 -> 100.2 µs.
// R6: R=4 rows/thread, KS=16 k-split: 4x fewer ds_read at same weight VGPRs;
//     16-lane folding reduce. FAILED absmax 2.5e-2: fold8/fold4 only summed
//     8/4 of the 16 lanes holding k-partials.
// R7: complete the reduce — fold8 + xor8; fold4 + xor4 + xor8 (lanes l,l^4,
//     l^8 hold the same value-index over disjoint subgroups). g_down too.

constexpr int NNODES = 1023;
constexpr int HB = 128;   // HID

// ---- folding cross-lane reduces within 16-lane groups ----
// a[NV] per-lane partials; every value needs the sum over ALL 16 lanes.
// fold16 alone is complete; fold8/fold4 need the extra xor stages (foldCH).
__device__ __forceinline__ float fold16(const float* a, int l) {
  float b[8];
#pragma unroll
  for (int u = 0; u < 8; ++u) {
    const float mine = (l & 1) ? a[2 * u + 1] : a[2 * u];
    const float oth  = (l & 1) ? a[2 * u]     : a[2 * u + 1];
    b[u] = mine + __shfl_xor(oth, 1);
  }
  float c[4];
#pragma unroll
  for (int u = 0; u < 4; ++u) {
    const float mine = (l & 2) ? b[2 * u + 1] : b[2 * u];
    const float oth  = (l & 2) ? b[2 * u]     : b[2 * u + 1];
    c[u] = mine + __shfl_xor(oth, 2);
  }
  float d[2];
#pragma unroll
  for (int u = 0; u < 2; ++u) {
    const float mine = (l & 4) ? c[2 * u + 1] : c[2 * u];
    const float oth  = (l & 4) ? c[2 * u]     : c[2 * u + 1];
    d[u] = mine + __shfl_xor(oth, 4);
  }
  const float mine = (l & 8) ? d[1] : d[0];
  const float oth  = (l & 8) ? d[0] : d[1];
  return mine + __shfl_xor(oth, 8);
}

__device__ __forceinline__ float fold8(const float* a, int l) {
  float b[4];
#pragma unroll
  for (int u = 0; u < 4; ++u) {
    const float mine = (l & 1) ? a[2 * u + 1] : a[2 * u];
    const float oth  = (l & 1) ? a[2 * u]     : a[2 * u + 1];
    b[u] = mine + __shfl_xor(oth, 1);
  }
  float c[2];
#pragma unroll
  for (int u = 0; u < 2; ++u) {
    const float mine = (l & 2) ? b[2 * u + 1] : b[2 * u];
    const float oth  = (l & 2) ? b[2 * u]     : b[2 * u + 1];
    c[u] = mine + __shfl_xor(oth, 2);
  }
  const float mine = (l & 4) ? c[1] : c[0];
  const float oth  = (l & 4) ? c[0] : c[1];
  return mine + __shfl_xor(oth, 4);
}

__device__ __forceinline__ float fold4(const float* a, int l) {
  float b[2];
#pragma unroll
  for (int u = 0; u < 2; ++u) {
    const float mine = (l & 1) ? a[2 * u + 1] : a[2 * u];
    const float oth  = (l & 1) ? a[2 * u]     : a[2 * u + 1];
    b[u] = mine + __shfl_xor(oth, 1);
  }
  const float mine = (l & 2) ? b[1] : b[0];
  const float oth  = (l & 2) ? b[0] : b[1];
  return mine + __shfl_xor(oth, 2);
}

// Complete 16-lane total for value v = l16 & (CH*4-1), landing on lane v
// (and its duplicates at v+CH*4, ...).
template<int CH>
__device__ __forceinline__ float foldCH(const float (&a)[CH * 4], int l16) {
  if constexpr (CH == 4) {
    return fold16(a, l16);
  } else if constexpr (CH == 2) {
    float t = fold8(a, l16);
    t += __shfl_xor(t, 8);             // other 8-lane half, same value index
    return t;
  } else {
    float t = fold4(a, l16);
    t += __shfl_xor(t, 4);             // complete the 16-lane sum
    t += __shfl_xor(t, 8);
    return t;
  }
}

// ---------- up pass: CH parents, out = tanh(Wc @ [h_l, h_r] + bc) ----------
// Thread: row-group g (rows 4g..4g+3), k-lane l16 (k-slice = floats
// l16*4 + 64m + e, m=0..3 of the 256-wide child ctx at node cb+2p).
// w[r][m] = Wc row 4g+r, that k-slice. bias_r = bc[4g + (l16&3)].
template<int CH>
__device__ __forceinline__ void up_pass(float* __restrict__ heap, int base, int cb,
                                        int cbase, const float4 (&w)[4][4],
                                        float bias_r, int g, int l16, bool wr) {
  float a[CH * 4];
#pragma unroll
  for (int v = 0; v < CH * 4; ++v) a[v] = 0.f;
#pragma unroll
  for (int p = 0; p < CH; ++p) {
    const float* cp = heap + (cb + 2 * (cbase + p)) * HB + l16 * 4;
#pragma unroll
    for (int m = 0; m < 4; ++m) {
      const float4 cc = *(const float4*)(cp + m * 64);
#pragma unroll
      for (int r = 0; r < 4; ++r) {
        const float4 wv = w[r][m];
        a[p * 4 + r] = fmaf(wv.x, cc.x, fmaf(wv.y, cc.y,
                        fmaf(wv.z, cc.z, fmaf(wv.w, cc.w, a[p * 4 + r]))));
      }
    }
  }
  const float tot = foldCH<CH>(a, l16);
  if (wr && l16 < CH * 4) {
    const int p = l16 >> 2;
    heap[(base + cbase + p) * HB + 4 * g + (l16 & 3)] = tanhf(tot + bias_r);
  }
}

// NH = thread-halves (1: all threads share parents; 2: halves take disjoint parents).
template<int NP, int NH>
__device__ __forceinline__ void up_level16(float* __restrict__ heap,
                                           const float4 (&w)[4][4],
                                           float bias_r, int g, int l16, int ph) {
  constexpr int base = NP - 1, cb = 2 * NP - 1;
  if constexpr (NP >= 4 * NH) {
#pragma unroll
    for (int c0 = 0; c0 < NP; c0 += 4 * NH)
      up_pass<4>(heap, base, cb, c0 + ph * 4, w, bias_r, g, l16, true);
  } else if constexpr (NP * 2 == 4 * NH) {
    up_pass<2>(heap, base, cb, ph * 2, w, bias_r, g, l16, true);
  } else if constexpr (NP == NH) {
    up_pass<1>(heap, base, cb, ph, w, bias_r, g, l16, true);
  } else {  // NP=1, NH=2: both halves compute, half 0 writes
    up_pass<1>(heap, base, cb, 0, w, bias_r, g, l16, ph == 0);
  }
  __syncthreads();
}

// ---------- down pass: ch = tanh(Wd @ [down_p, up_p] + bd) ----------
// ctx k: m=0,1 -> down[l16*4 + 64m]; m=2,3 -> up[l16*4 + 64(m-2)].
// Lane l16 writes (parent cbase+(l16>>2), output row 4g+(l16&3)); row<128 ->
// left child, else right.
template<int CH>
__device__ __forceinline__ void down_pass(float* __restrict__ db,
                                          const float* __restrict__ ub,
                                          int base, int cb, int cbase,
                                          const float4 (&w)[4][4],
                                          float bias_r, int g, int l16) {
  float a[CH * 4];
#pragma unroll
  for (int v = 0; v < CH * 4; ++v) a[v] = 0.f;
#pragma unroll
  for (int p = 0; p < CH; ++p) {
    const float* dp = db + (base + cbase + p) * HB + l16 * 4;
    const float* up = ub + (base + cbase + p) * HB + l16 * 4;
#pragma unroll
    for (int m = 0; m < 4; ++m) {
      const float4 cc = *(const float4*)(((m < 2) ? dp : up) + (m & 1) * 64);
#pragma unroll
      for (int r = 0; r < 4; ++r) {
        const float4 wv = w[r][m];
        a[p * 4 + r] = fmaf(wv.x, cc.x, fmaf(wv.y, cc.y,
                        fmaf(wv.z, cc.z, fmaf(wv.w, cc.w, a[p * 4 + r]))));
      }
    }
  }
  const float tot = foldCH<CH>(a, l16);
  if (l16 < CH * 4) {
    const int p = l16 >> 2;
    const int row = 4 * g + (l16 & 3);     // 0..255
    db[(cb + 2 * (cbase + p) + (row >> 7)) * HB + (row & 127)] = tanhf(tot + bias_r);
  }
}

template<int NP>
__device__ __forceinline__ void down_level16(float* __restrict__ db,
                                             const float* __restrict__ ub,
                                             const float4 (&w)[4][4],
                                             float bias_r, int g, int l16) {
  constexpr int base = NP - 1, cb = 2 * NP - 1;
  if constexpr (NP >= 4) {
#pragma unroll
    for (int c0 = 0; c0 < NP; c0 += 4)
      down_pass<4>(db, ub, base, cb, c0, w, bias_r, g, l16);
  } else {
    down_pass<NP>(db, ub, base, cb, 0, w, bias_r, g, l16);
  }
  __syncthreads();
}

// ---------- classifier, 16 threads/node, float4 loads + shfl reduce ----------
__device__ __forceinline__ void classify16(const float* __restrict__ dn,
                                           const float* __restrict__ un,
                                           const float* __restrict__ wcl,
                                           const float* __restrict__ bcl,
                                           float* __restrict__ o, int l16) {
  const int k0 = l16 * 8;
  float s0, s1;
  {
    const float4 d0 = *(const float4*)(dn + k0);
    const float4 d1 = *(const float4*)(dn + k0 + 4);
    const float4 a0 = *(const float4*)(wcl + k0);
    const float4 a1 = *(const float4*)(wcl + k0 + 4);
    const float4 b0 = *(const float4*)(wcl + 256 + k0);
    const float4 b1 = *(const float4*)(wcl + 256 + k0 + 4);
    s0 = d0.x * a0.x + d0.y * a0.y + d0.z * a0.z + d0.w * a0.w
       + d1.x * a1.x + d1.y * a1.y + d1.z * a1.z + d1.w * a1.w;
    s1 = d0.x * b0.x + d0.y * b0.y + d0.z * b0.z + d0.w * b0.w
       + d1.x * b1.x + d1.y * b1.y + d1.z * b1.z + d1.w * b1.w;
  }
  if (un) {
    const float4 u0 = *(const float4*)(un + k0);
    const float4 u1 = *(const float4*)(un + k0 + 4);
    const float4 a0 = *(const float4*)(wcl + 128 + k0);
    const float4 a1 = *(const float4*)(wcl + 128 + k0 + 4);
    const float4 b0 = *(const float4*)(wcl + 384 + k0);
    const float4 b1 = *(const float4*)(wcl + 384 + k0 + 4);
    s0 += u0.x * a0.x + u0.y * a0.y + u0.z * a0.z + u0.w * a0.w
        + u1.x * a1.x + u1.y * a1.y + u1.z * a1.z + u1.w * a1.w;
    s1 += u0.x * b0.x + u0.y * b0.y + u0.z * b0.z + u0.w * b0.w
        + u1.x * b1.x + u1.y * b1.y + u1.z * b1.z + u1.w * b1.w;
  }
#pragma unroll
  for (int m = 8; m >= 1; m >>= 1) {
    s0 += __shfl_xor(s0, m);
    s1 += __shfl_xor(s1, m);
  }
  if (l16 == 0) {
    s0 += bcl[0]; s1 += bcl[1];
    const float p0 = 1.f / (1.f + expf(-s0));
    const float p1 = 1.f / (1.f + expf(-s1));
    const float mx = fmaxf(p0, p1);
    const float e0 = expf(p0 - mx), e1 = expf(p1 - mx);
    const float inv = 1.f / (e0 + e1);
    o[0] = e0 * inv;
    o[1] = e1 * inv;
  }
}

// ================= Kernel A: leaf gather + up levels 8..4 =================
// grid = 32*16 (batch, level-4 subtree); 512 thr: g = t>>4 (0..31), l16 = t&15.
// ~60 KB LDS -> 2 blocks/CU (pins RA occupancy target at 4 waves/SIMD).
__global__ __launch_bounds__(512, 4) void kA_up(const int* __restrict__ x,
                                                const int* __restrict__ cue,
                                                const float* __restrict__ emb,
                                                const float* __restrict__ Wc,
                                                const float* __restrict__ bc,
                                                float* __restrict__ hw) {
  __shared__ __align__(16) float heap[63 * HB];
  __shared__ __align__(16) float pad[7296];   // unused; pins occupancy via LDS
  const int b = blockIdx.x >> 4, s = blockIdx.x & 15, r = 15 + s;
  const int t = threadIdx.x, g = t >> 4, l16 = t & 15;
  if (t == 0) ((volatile float*)pad)[0] = 0.f;

  float4 w[4][4];
#pragma unroll
  for (int rr = 0; rr < 4; ++rr)
#pragma unroll
    for (int m = 0; m < 4; ++m)
      w[rr][m] = *(const float4*)(Wc + (4 * g + rr) * 256 + l16 * 4 + m * 64);
  const float bias_r = bc[4 * g + (l16 & 3)];

  // leaf features: [emb[x] (126) | one_hot(cue,2)]
  for (int idx = t; idx < 32 * HB; idx += 512) {
    const int j = idx >> 7, k = idx & 127;
    const int gq = ((r + 1) << 5) - 1 + j;     // global leaf node (511..1022)
    float v;
    if (k < 126) v = emb[(long long)x[b * NNODES + gq] * 126 + k];
    else         v = (cue[b * NNODES + gq] == (k - 126)) ? 1.f : 0.f;
    heap[(31 + j) * HB + k] = v;
  }
  __syncthreads();

  up_level16<16, 1>(heap, w, bias_r, g, l16, 0);
  up_level16<8, 1>(heap, w, bias_r, g, l16, 0);
  up_level16<4, 1>(heap, w, bias_r, g, l16, 0);
  up_level16<2, 1>(heap, w, bias_r, g, l16, 0);
  up_level16<1, 1>(heap, w, bias_r, g, l16, 0);

  float4* dst = (float4*)(hw + (size_t)(b * 16 + s) * 31 * HB);
  const float4* src = (const float4*)heap;
  for (int idx = t; idx < 31 * 32; idx += 512) dst[idx] = src[idx];
}

// ================= Kernel B: up 3..0, g_down, down 0..3, classify 0..14 =================
// 1024 thr, one block per batch. Up: rows 128 -> 2 thread-halves on disjoint
// parents. Down: rows 256 -> all threads. >80 KB LDS -> 1 block/CU.
__global__ __launch_bounds__(1024, 4) void kB_mid(const float* __restrict__ Wc,
                                                  const float* __restrict__ bc,
                                                  const float* __restrict__ Wg,
                                                  const float* __restrict__ bg,
                                                  const float* __restrict__ Wd,
                                                  const float* __restrict__ bd,
                                                  const float* __restrict__ Wcl,
                                                  const float* __restrict__ bcl,
                                                  const float* __restrict__ hw,
                                                  float* __restrict__ dw,
                                                  float* __restrict__ out) {
  __shared__ __align__(16) float ub[31 * HB];   // up h, nodes 0..30
  __shared__ __align__(16) float db[31 * HB];   // down, nodes 0..30
  __shared__ __align__(16) float pad[12084];    // unused; pins occupancy via LDS
  __shared__ __align__(16) float wcl[512];
  const int b = blockIdx.x, t = threadIdx.x;
  if (t == 0) ((volatile float*)pad)[0] = 0.f;

  // level-4 h (root of each subtree s) -> ub[15..30]  (float4 staging)
  {
    float4* u4 = (float4*)(ub + 15 * HB);
    for (int idx = t; idx < 16 * 32; idx += 1024) {
      const int s = idx >> 5, k4 = idx & 31;
      u4[idx] = ((const float4*)(hw + (size_t)(b * 16 + s) * 31 * HB))[k4];
    }
  }
  if (t < 512) wcl[t] = Wcl[t];
  __syncthreads();

  // ---- up levels 3..0 (rows 128: g = (t>>4)&31, halves ph on parents) ----
  {
    const int g = (t >> 4) & 31, l16 = t & 15, ph = t >> 9;
    float4 w[4][4];
#pragma unroll
    for (int rr = 0; rr < 4; ++rr)
#pragma unroll
      for (int m = 0; m < 4; ++m)
        w[rr][m] = *(const float4*)(Wc + (4 * g + rr) * 256 + l16 * 4 + m * 64);
    const float bias_r = bc[4 * g + (l16 & 3)];
    up_level16<8, 2>(ub, w, bias_r, g, l16, ph);
    up_level16<4, 2>(ub, w, bias_r, g, l16, ph);
    up_level16<2, 2>(ub, w, bias_r, g, l16, ph);
    up_level16<1, 2>(ub, w, bias_r, g, l16, ph);

    // g_down = sigmoid(Wg @ h_root + bg): 128-wide ctx, k-slices l16*4+64m, m=0..1
    float4 wg[4][2];
#pragma unroll
    for (int rr = 0; rr < 4; ++rr)
#pragma unroll
      for (int m = 0; m < 2; ++m)
        wg[rr][m] = *(const float4*)(Wg + (4 * g + rr) * 128 + l16 * 4 + m * 64);
    float a[4];
#pragma unroll
    for (int v = 0; v < 4; ++v) a[v] = 0.f;
#pragma unroll
    for (int m = 0; m < 2; ++m) {
      const float4 cc = *(const float4*)(ub + l16 * 4 + m * 64);
#pragma unroll
      for (int rr = 0; rr < 4; ++rr) {
        const float4 wv = wg[rr][m];
        a[rr] = fmaf(wv.x, cc.x, fmaf(wv.y, cc.y, fmaf(wv.z, cc.z, fmaf(wv.w, cc.w, a[rr]))));
      }
    }
    float tot = fold4(a, l16);
    tot += __shfl_xor(tot, 4);           // complete the 16-lane sum (R7 fix)
    tot += __shfl_xor(tot, 8);
    if (ph == 0 && l16 < 4) {
      const int row = 4 * g + l16;
      db[row] = 1.f / (1.f + expf(-(tot + bg[row])));
    }
    __syncthreads();
  }
  asm volatile("" ::: "memory");  // keep Wd loads from hoisting into the up phase

  // ---- down levels 0..3 (rows 256: g = t>>4) ----
  {
    const int g = t >> 4, l16 = t & 15;
    float4 w[4][4];
#pragma unroll
    for (int rr = 0; rr < 4; ++rr)
#pragma unroll
      for (int m = 0; m < 4; ++m)
        w[rr][m] = *(const float4*)(Wd + (4 * g + rr) * 256 + l16 * 4 + m * 64);
    const float bias_r = bd[4 * g + (l16 & 3)];
    down_level16<1>(db, ub, w, bias_r, g, l16);
    down_level16<2>(db, ub, w, bias_r, g, l16);
    down_level16<4>(db, ub, w, bias_r, g, l16);
    down_level16<8>(db, ub, w, bias_r, g, l16);
  }

  // persist level-4 down (nodes 15..30) for kernel C  (float4)
  {
    const float4* s4 = (const float4*)(db + 15 * HB);
    float4* d4 = (float4*)dw;
    for (int idx = t; idx < 16 * 32; idx += 1024)
      d4[(size_t)b * 16 * 32 + idx] = s4[idx];
  }

  // classify global nodes 0..14 (16 threads per node)
  if (t < 15 * 16) {
    const int m = t >> 4;
    classify16(db + m * HB, ub + m * HB, wcl, bcl,
               out + ((size_t)b * NNODES + m) * 2, t & 15);
  }
}

// ================= Kernel C: down levels 4..8 + classify 63 subtree nodes =================
// 1024 thr: g = t>>4 (0..63), l16 = t&15. >80 KB LDS -> 1 block/CU.
__global__ __launch_bounds__(1024, 4) void kC_down(const float* __restrict__ Wd,
                                                   const float* __restrict__ bd,
                                                   const float* __restrict__ Wcl,
                                                   const float* __restrict__ bcl,
                                                   const float* __restrict__ hw,
                                                   const float* __restrict__ dw,
                                                   float* __restrict__ out) {
  __shared__ __align__(16) float ub[31 * HB];   // up h, local nodes 0..30
  __shared__ __align__(16) float db[63 * HB];   // down, local nodes 0..62
  __shared__ __align__(16) float pad[7960];     // unused; pins occupancy via LDS
  __shared__ __align__(16) float wcl[512];
  const int b = blockIdx.x >> 4, s = blockIdx.x & 15, r = 15 + s;
  const int t = threadIdx.x, g = t >> 4, l16 = t & 15;
  if (t == 0) ((volatile float*)pad)[0] = 0.f;

  float4 w[4][4];
#pragma unroll
  for (int rr = 0; rr < 4; ++rr)
#pragma unroll
    for (int m = 0; m < 4; ++m)
      w[rr][m] = *(const float4*)(Wd + (4 * g + rr) * 256 + l16 * 4 + m * 64);
  const float bias_r = bd[4 * g + (l16 & 3)];

  {
    const float4* s4 = (const float4*)(hw + (size_t)(b * 16 + s) * 31 * HB);
    float4* u4 = (float4*)ub;
    for (int idx = t; idx < 31 * 32; idx += 1024) u4[idx] = s4[idx];
    const float4* dv = (const float4*)(dw + (size_t)(b * 16 + s) * HB);
    if (t < 32) ((float4*)db)[t] = dv[t];      // down at subtree root
  }
  if (t < 512) wcl[t] = Wcl[t];
  __syncthreads();

  down_level16<1>(db, ub, w, bias_r, g, l16);
  down_level16<2>(db, ub, w, bias_r, g, l16);
  down_level16<4>(db, ub, w, bias_r, g, l16);
  down_level16<8>(db, ub, w, bias_r, g, l16);
  down_level16<16>(db, ub, w, bias_r, g, l16);

  // classify local heap nodes 0..62 (16 threads per node); leaves have up = 0
  if (t < 63 * 16) {
    const int m = t >> 4;
    const int lvl = 31 - __clz(m + 1);
    const int j = (m + 1) - (1 << lvl);
    const int gq = ((r + 1) << lvl) - 1 + j;
    classify16(db + m * HB, (m < 31) ? (ub + m * HB) : nullptr, wcl, bcl,
               out + ((size_t)b * NNODES + gq) * 2, t & 15);
  }
}

extern "C" void kernel_launch(void* const* d_in, const int* in_sizes, int n_in,
                              void* d_out, int out_size, void* d_ws, size_t ws_size,
                              hipStream_t stream) {
  const int*   x   = (const int*)d_in[0];
  // d_in[1] word_index: identity leaf mapping (leaf j at node 511+j) -- unused
  const int*   cue = (const int*)d_in[2];
  // d_in[3] adj: encodes the same hardcoded heap tree -- unused
  const float* emb = (const float*)d_in[4];
  const float* Wc  = (const float*)d_in[5];
  const float* bc  = (const float*)d_in[6];
  const float* Wd  = (const float*)d_in[7];
  const float* bd  = (const float*)d_in[8];
  const float* Wg  = (const float*)d_in[9];
  const float* bg  = (const float*)d_in[10];
  const float* Wcl = (const float*)d_in[11];
  const float* bcl = (const float*)d_in[12];
  float* out = (float*)d_out;

  float* hw = (float*)d_ws;                       // [B][16][31][128] up h
  float* dw = hw + (size_t)32 * 16 * 31 * 128;    // [B][16][128] level-4 down

  hipLaunchKernelGGL(kA_up,   dim3(512), dim3(512), 0, stream, x, cue, emb, Wc, bc, hw);
  hipLaunchKernelGGL(kB_mid,  dim3(32),  dim3(1024), 0, stream,
                     Wc, bc, Wg, bg, Wd, bd, Wcl, bcl, hw, dw, out);
  hipLaunchKernelGGL(kC_down, dim3(512), dim3(1024), 0, stream,
                     Wd, bd, Wcl, bcl, hw, dw, out);
}